// Round 5
// baseline (198.686 us; speedup 1.0000x reference)
//
#include <hip/hip_runtime.h>
#include <hip/hip_bf16.h>

typedef __bf16 bf16_t;
typedef __bf16 bf16x8 __attribute__((ext_vector_type(8)));
typedef float f32x4 __attribute__((ext_vector_type(4)));
typedef unsigned int u32;

#define NB 16
#define HW 56
#define DIM 192
#define N3 576
#define WS7 7
#define HEADS 6
#define HD 32
#define NTOK 49
#define MFMA(a, b, c) __builtin_amdgcn_mfma_f32_16x16x32_bf16(a, b, c, 0, 0, 0)

__device__ __forceinline__ void gld_lds16(const bf16_t* g, bf16_t* l) {
    __builtin_amdgcn_global_load_lds((const __attribute__((address_space(1))) u32*)g,
                                     (__attribute__((address_space(3))) u32*)l, 16, 0, 0);
}

// ---------------- prep: transpose+cast weights to [n][k] bf16 ----------------
__global__ __launch_bounds__(256) void prep_w_kernel(const float* __restrict__ wqkv,
                                                     const float* __restrict__ wout,
                                                     bf16_t* __restrict__ wqkvt,
                                                     bf16_t* __restrict__ woutt) {
    int idx = blockIdx.x * 256 + threadIdx.x;
    if (idx < N3 * DIM) {
        int k = idx % DIM, n = idx / DIM;
        wqkvt[idx] = (bf16_t)wqkv[(size_t)k * N3 + n];
    } else {
        int j = idx - N3 * DIM;
        if (j < DIM * DIM) {
            int k = j % DIM, n = j / DIM;
            woutt[j] = (bf16_t)wout[(size_t)k * DIM + n];
        }
    }
}

// ---------------- prep: bias+shift-mask tables  tbl[4][64][64] f32 ----------------
// variant bit1 = maskrow (wh==7), bit0 = maskcol (ww==7); -1e9 for masked / OOB
__global__ __launch_bounds__(256) void prep_tbl_kernel(const float* __restrict__ pe,
                                                       float* __restrict__ tbl) {
    int idx = blockIdx.x * 256 + threadIdx.x;     // 4*64*64 = 16384
    if (idx >= 4 * 64 * 64) return;
    int v = idx >> 12, rem = idx & 4095, ti = rem >> 6, tj = rem & 63;
    float val = -1e9f;
    if (ti < NTOK && tj < NTOK) {
        int yi = ti / 7, xi = ti % 7, yj = tj / 7, xj = tj % 7;
        val = pe[(yj - yi + 6) * 13 + (xj - xi + 6)];
        bool mr = (v & 2) && ((yi >= 4) != (yj >= 4));
        bool mc = (v & 1) && ((xi >= 4) != (xj >= 4));
        if (mr || mc) val = -1e9f;
    }
    tbl[idx] = val;
}

// ---------------- K1: QKV GEMM fused with roll(-3,-3) + fp32->bf16 ----------------
// C[50176,576] = roll(x) @ wqkvt^T.  256x64 tile; B via global_load_lds + XOR swizzle;
// A loaded fp32 from x with roll applied in the row map, converted in-register.
// q columns (nblk<3) prescaled by 1/sqrt(d).
__global__ __launch_bounds__(256) void qkv_gemm4(const float* __restrict__ x,
                                                 const bf16_t* __restrict__ wt,
                                                 bf16_t* __restrict__ qkv) {
    __shared__ alignas(16) bf16_t bsh[64 * DIM];     // 24576 B, swizzled layout
    const int mblk = blockIdx.x, nblk = blockIdx.y;
    const int wave = threadIdx.x >> 6, lane = threadIdx.x & 63;
    const int lo = lane & 15, hi = lane >> 4;

    const bf16_t* bt = wt + (size_t)nblk * 64 * DIM;
#pragma unroll
    for (int i = 0; i < 6; i++) {
        int s = wave * 384 + i * 64 + lane;          // 16B chunk index
        int g = s ^ ((s / 24) & 7);                  // pre-swizzled source
        gld_lds16(bt + g * 8, bsh + (wave * 384 + i * 64) * 8);
    }

    // A fragments: fp32 loads with roll row-map, cvt to bf16 in-register
    bf16x8 a[4][6];
#pragma unroll
    for (int mt = 0; mt < 4; mt++) {
        int m = mblk * 256 + wave * 64 + mt * 16 + lo;
        int bb = m / (HW * HW);
        int rem = m - bb * HW * HW;
        int yy = rem / HW, xx = rem - (rem / HW) * HW;
        int ys = yy + 3; if (ys >= HW) ys -= HW;
        int xs = xx + 3; if (xs >= HW) xs -= HW;
        const float* src = x + ((size_t)(bb * HW + ys) * HW + xs) * DIM + hi * 8;
#pragma unroll
        for (int ks = 0; ks < 6; ks++) {
            float4 f0 = *reinterpret_cast<const float4*>(src + ks * 32);
            float4 f1 = *reinterpret_cast<const float4*>(src + ks * 32 + 4);
            bf16x8 o;
            o[0] = (bf16_t)f0.x; o[1] = (bf16_t)f0.y; o[2] = (bf16_t)f0.z; o[3] = (bf16_t)f0.w;
            o[4] = (bf16_t)f1.x; o[5] = (bf16_t)f1.y; o[6] = (bf16_t)f1.z; o[7] = (bf16_t)f1.w;
            a[mt][ks] = o;
        }
    }

    f32x4 acc[4][4];
#pragma unroll
    for (int mt = 0; mt < 4; mt++)
#pragma unroll
        for (int ct = 0; ct < 4; ct++) acc[mt][ct] = (f32x4){0.f, 0.f, 0.f, 0.f};

    __syncthreads();

#pragma unroll
    for (int ks = 0; ks < 6; ks++)
#pragma unroll
        for (int ct = 0; ct < 4; ct++) {
            int r = ct * 16 + lo;
            int off = (ks * 64 + hi * 16) ^ ((r & 7) << 4);   // swizzled read
            bf16x8 b = *reinterpret_cast<const bf16x8*>((const char*)bsh + r * 384 + off);
#pragma unroll
            for (int mt = 0; mt < 4; mt++)
                acc[mt][ct] = MFMA(a[mt][ks], b, acc[mt][ct]);
        }

    const float qs = (nblk < 3) ? 0.17677669529663687f : 1.0f;   // 1/sqrt(32)
    const size_t rb = (size_t)mblk * 256 + wave * 64;
#pragma unroll
    for (int mt = 0; mt < 4; mt++)
#pragma unroll
        for (int ct = 0; ct < 4; ct++)
#pragma unroll
            for (int r = 0; r < 4; r++)
                qkv[(rb + mt * 16 + hi * 4 + r) * N3 + nblk * 64 + ct * 16 + lo] =
                    (bf16_t)(acc[mt][ct][r] * qs);
}

// ---------------- K2: attention, 4 waves cooperate on one (window,head) ----------------
// wave mt owns output rows mt*16..mt*16+15: 4 QK MFMAs, 4 softmax rows, 4 PV MFMAs.
__global__ __launch_bounds__(256) void attn_kernel4(const bf16_t* __restrict__ qkv,
                                                    const float* __restrict__ tbl,
                                                    bf16_t* __restrict__ att) {
    const int win = blockIdx.x, h = blockIdx.y, bb = blockIdx.z;
    const int wh = win >> 3, ww = win & 7;
    const int mt = threadIdx.x >> 6;                  // wave id = M-tile id
    const int lane = threadIdx.x & 63;
    const int lo = lane & 15, hi = lane >> 4;

    __shared__ bf16_t P[64][72];                      // per-wave rows; stride 72
    __shared__ alignas(16) bf16_t VT[32][72];         // V transposed [d][token]

    const int variant = ((wh == 7) ? 2 : 0) | ((ww == 7) ? 1 : 0);
    const float* tbase = tbl + ((size_t)variant << 12);

    auto tokoff = [&](int t) -> size_t {
        int ti = t / 7, tj = t % 7;
        return ((size_t)(bb * HW + wh * WS7 + ti) * HW + ww * WS7 + tj) * N3 + h * HD;
    };

    // stage V transposed: thread (mt,lo,hi) loads token t=mt*16+lo, channels hi*8..+8
    {
        const int t = mt * 16 + lo;
        bf16x8 v;
        if (t < NTOK) {
            v = *reinterpret_cast<const bf16x8*>(qkv + tokoff(t) + 2 * DIM + hi * 8);
        } else {
#pragma unroll
            for (int j = 0; j < 8; j++) v[j] = (bf16_t)0.f;
        }
#pragma unroll
        for (int j = 0; j < 8; j++) VT[hi * 8 + j][t] = v[j];
    }

    // Q (own M-tile rows) and K (all 4 column tiles); q pre-scaled in GEMM
    bf16x8 qf, kf[4];
    {
        int t = mt * 16 + lo;
        if (t < NTOK) {
            qf = *reinterpret_cast<const bf16x8*>(qkv + tokoff(t) + hi * 8);
        } else {
#pragma unroll
            for (int j = 0; j < 8; j++) qf[j] = (bf16_t)0.f;
        }
    }
#pragma unroll
    for (int ct = 0; ct < 4; ct++) {
        int t = ct * 16 + lo;
        if (t < NTOK) {
            kf[ct] = *reinterpret_cast<const bf16x8*>(qkv + tokoff(t) + DIM + hi * 8);
        } else {
#pragma unroll
            for (int j = 0; j < 8; j++) kf[ct][j] = (bf16_t)0.f;
        }
    }

    const f32x4 zero4 = {0.f, 0.f, 0.f, 0.f};
    f32x4 s[4];
#pragma unroll
    for (int ct = 0; ct < 4; ct++) s[ct] = MFMA(qf, kf[ct], zero4);

    // softmax over this wave's 4 row-groups
    float rinv[4];
#pragma unroll
    for (int r = 0; r < 4; r++) {
        int ti = mt * 16 + hi * 4 + r;
        const float* trow = tbase + ti * 64 + lo;
        float vals[4];
        float mx = -3e38f;
#pragma unroll
        for (int ct = 0; ct < 4; ct++) {
            float v = s[ct][r] + trow[ct * 16];
            vals[ct] = v;
            mx = fmaxf(mx, v);
        }
#pragma unroll
        for (int off = 1; off < 16; off <<= 1) mx = fmaxf(mx, __shfl_xor(mx, off));
        float sum = 0.f;
#pragma unroll
        for (int ct = 0; ct < 4; ct++) {
            float p = __expf(vals[ct] - mx);
            sum += p;
            P[ti][ct * 16 + lo] = (bf16_t)p;
        }
#pragma unroll
        for (int off = 1; off < 16; off <<= 1) sum += __shfl_xor(sum, off);
        rinv[r] = 1.f / sum;
    }

    __syncthreads();   // VT complete (P rows are wave-local, lgkmcnt suffices)

    // O(16x32) = P(16x64) @ V(64x32): 2 K-steps x 2 col-tiles
    f32x4 o[2] = {zero4, zero4};
#pragma unroll
    for (int ks = 0; ks < 2; ks++) {
        bf16x8 pa = *reinterpret_cast<const bf16x8*>(&P[mt * 16 + lo][ks * 32 + hi * 8]);
#pragma unroll
        for (int c2 = 0; c2 < 2; c2++) {
            bf16x8 vb = *reinterpret_cast<const bf16x8*>(&VT[c2 * 16 + lo][ks * 32 + hi * 8]);
            o[c2] = MFMA(pa, vb, o[c2]);
        }
    }

#pragma unroll
    for (int r = 0; r < 4; r++) {
        int ti = mt * 16 + hi * 4 + r;
        if (ti < NTOK) {
            int y = wh * WS7 + ti / 7, xcol = ww * WS7 + ti % 7;
            size_t aoff = ((size_t)(bb * HW + y) * HW + xcol) * DIM + h * HD;
#pragma unroll
            for (int c2 = 0; c2 < 2; c2++)
                att[aoff + c2 * 16 + lo] = (bf16_t)(o[c2][r] * rinv[r]);
        }
    }
}

// ---------------- K3: out GEMM + bias + roll(+3,+3) ----------------
__global__ __launch_bounds__(256) void out_gemm2(const bf16_t* __restrict__ att,
                                                 const bf16_t* __restrict__ wt,
                                                 const float* __restrict__ bias,
                                                 float* __restrict__ out) {
    __shared__ alignas(16) bf16_t bsh[64 * DIM];
    const int mblk = blockIdx.x, nblk = blockIdx.y;
    const int wave = threadIdx.x >> 6, lane = threadIdx.x & 63;
    const int lo = lane & 15, hi = lane >> 4;

    const bf16_t* bt = wt + (size_t)nblk * 64 * DIM;
#pragma unroll
    for (int i = 0; i < 6; i++) {
        int s = wave * 384 + i * 64 + lane;
        int g = s ^ ((s / 24) & 7);
        gld_lds16(bt + g * 8, bsh + (wave * 384 + i * 64) * 8);
    }

    bf16x8 a[2][6];
    const bf16_t* ab = att + ((size_t)mblk * 128 + wave * 32 + lo) * DIM + hi * 8;
#pragma unroll
    for (int mt = 0; mt < 2; mt++)
#pragma unroll
        for (int ks = 0; ks < 6; ks++)
            a[mt][ks] = *reinterpret_cast<const bf16x8*>(ab + mt * 16 * DIM + ks * 32);

    f32x4 acc[2][4];
#pragma unroll
    for (int mt = 0; mt < 2; mt++)
#pragma unroll
        for (int ct = 0; ct < 4; ct++) acc[mt][ct] = (f32x4){0.f, 0.f, 0.f, 0.f};

    __syncthreads();

#pragma unroll
    for (int ks = 0; ks < 6; ks++)
#pragma unroll
        for (int ct = 0; ct < 4; ct++) {
            int r = ct * 16 + lo;
            int off = (ks * 64 + hi * 16) ^ ((r & 7) << 4);
            bf16x8 b = *reinterpret_cast<const bf16x8*>((const char*)bsh + r * 384 + off);
            acc[0][ct] = MFMA(a[0][ks], b, acc[0][ct]);
            acc[1][ct] = MFMA(a[1][ks], b, acc[1][ct]);
        }

    const int rb = mblk * 128 + wave * 32;
#pragma unroll
    for (int mt = 0; mt < 2; mt++)
#pragma unroll
        for (int r = 0; r < 4; r++) {
            int m = rb + mt * 16 + hi * 4 + r;
            int bb = m / (HW * HW);
            int rem = m - bb * HW * HW;
            int ya = rem / HW, xa = rem - ya * HW;
            int yo = ya + 3; if (yo >= HW) yo -= HW;
            int xo = xa + 3; if (xo >= HW) xo -= HW;
            size_t ob = ((size_t)(bb * HW + yo) * HW + xo) * DIM + nblk * 64;
#pragma unroll
            for (int ct = 0; ct < 4; ct++)
                out[ob + ct * 16 + lo] = acc[mt][ct][r] + bias[nblk * 64 + ct * 16 + lo];
        }
}

extern "C" void kernel_launch(void* const* d_in, const int* in_sizes, int n_in,
                              void* d_out, int out_size, void* d_ws, size_t ws_size,
                              hipStream_t stream) {
    const float* x    = (const float*)d_in[0];
    const float* wqkv = (const float*)d_in[1];
    const float* pe   = (const float*)d_in[2];
    const float* wout = (const float*)d_in[3];
    const float* bout = (const float*)d_in[4];
    float* out = (float*)d_out;

    char* ws = (char*)d_ws;
    const size_t QKV_BYTES = (size_t)NB * HW * HW * N3 * 2;    // 57,802,752
    const size_t ATT_BYTES = (size_t)NB * HW * HW * DIM * 2;   // 19,267,584
    const size_t WQ_BYTES  = (size_t)N3 * DIM * 2;
    const size_t WO_BYTES  = (size_t)DIM * DIM * 2;
    bf16_t* qkv   = (bf16_t*)ws;
    bf16_t* att   = (bf16_t*)(ws + QKV_BYTES);
    bf16_t* wqkvt = (bf16_t*)(ws + QKV_BYTES + ATT_BYTES);
    bf16_t* woutt = (bf16_t*)(ws + QKV_BYTES + ATT_BYTES + WQ_BYTES);
    float*  tbl   = (float*)(ws + QKV_BYTES + ATT_BYTES + WQ_BYTES + WO_BYTES);

    prep_w_kernel<<<(N3 * DIM + DIM * DIM + 255) / 256, 256, 0, stream>>>(wqkv, wout, wqkvt, woutt);
    prep_tbl_kernel<<<64, 256, 0, stream>>>(pe, tbl);
    qkv_gemm4<<<dim3(196, 9), 256, 0, stream>>>(x, wqkvt, qkv);
    attn_kernel4<<<dim3(64, HEADS, NB), 256, 0, stream>>>(qkv, tbl, att);
    out_gemm2<<<dim3(392, 3), 256, 0, stream>>>(att, woutt, bout, out);
}

// Round 6
// 176.650 us; speedup vs baseline: 1.1247x; 1.1247x over previous
//
#include <hip/hip_runtime.h>
#include <hip/hip_bf16.h>

typedef __bf16 bf16_t;
typedef __bf16 bf16x8 __attribute__((ext_vector_type(8)));
typedef float f32x4 __attribute__((ext_vector_type(4)));
typedef unsigned int u32;

#define NB 16
#define HW 56
#define DIM 192
#define N3 576
#define WS7 7
#define HEADS 6
#define HD 32
#define NTOK 49
#define MFMA(a, b, c) __builtin_amdgcn_mfma_f32_16x16x32_bf16(a, b, c, 0, 0, 0)

__device__ __forceinline__ void gld_lds16(const bf16_t* g, bf16_t* l) {
    __builtin_amdgcn_global_load_lds((const __attribute__((address_space(1))) u32*)g,
                                     (__attribute__((address_space(3))) u32*)l, 16, 0, 0);
}

// ---------------- prep: roll(-3,-3) + fp32->bf16 of x ----------------
__global__ __launch_bounds__(256) void prep_x_kernel(const float* __restrict__ x,
                                                     bf16_t* __restrict__ xb) {
    int idx = blockIdx.x * 256 + threadIdx.x;
    const int total = NB * HW * HW * (DIM / 8);
    if (idx >= total) return;
    int c8 = idx % (DIM / 8);
    int p  = idx / (DIM / 8);
    int xx = p % HW;
    int yy = (p / HW) % HW;
    int bb = p / (HW * HW);
    int ys = yy + 3; if (ys >= HW) ys -= HW;
    int xs = xx + 3; if (xs >= HW) xs -= HW;
    const float* src = x + ((size_t)(bb * HW + ys) * HW + xs) * DIM + c8 * 8;
    float4 a0 = *reinterpret_cast<const float4*>(src);
    float4 a1 = *reinterpret_cast<const float4*>(src + 4);
    bf16x8 o;
    o[0] = (bf16_t)a0.x; o[1] = (bf16_t)a0.y; o[2] = (bf16_t)a0.z; o[3] = (bf16_t)a0.w;
    o[4] = (bf16_t)a1.x; o[5] = (bf16_t)a1.y; o[6] = (bf16_t)a1.z; o[7] = (bf16_t)a1.w;
    *reinterpret_cast<bf16x8*>(xb + (size_t)idx * 8) = o;
}

// ---------------- prep: transpose+cast weights to [n][k] bf16 ----------------
__global__ __launch_bounds__(256) void prep_w_kernel(const float* __restrict__ wqkv,
                                                     const float* __restrict__ wout,
                                                     bf16_t* __restrict__ wqkvt,
                                                     bf16_t* __restrict__ woutt) {
    int idx = blockIdx.x * 256 + threadIdx.x;
    if (idx < N3 * DIM) {
        int k = idx % DIM, n = idx / DIM;
        wqkvt[idx] = (bf16_t)wqkv[(size_t)k * N3 + n];
    } else {
        int j = idx - N3 * DIM;
        if (j < DIM * DIM) {
            int k = j % DIM, n = j / DIM;
            woutt[j] = (bf16_t)wout[(size_t)k * DIM + n];
        }
    }
}

// ---------------- prep: bias+shift-mask tables  tbl[4][64][64] f32 ----------------
__global__ __launch_bounds__(256) void prep_tbl_kernel(const float* __restrict__ pe,
                                                       float* __restrict__ tbl) {
    int idx = blockIdx.x * 256 + threadIdx.x;     // 4*64*64 = 16384
    if (idx >= 4 * 64 * 64) return;
    int v = idx >> 12, rem = idx & 4095, ti = rem >> 6, tj = rem & 63;
    float val = -1e9f;
    if (ti < NTOK && tj < NTOK) {
        int yi = ti / 7, xi = ti % 7, yj = tj / 7, xj = tj % 7;
        val = pe[(yj - yi + 6) * 13 + (xj - xi + 6)];
        bool mr = (v & 2) && ((yi >= 4) != (yj >= 4));
        bool mc = (v & 1) && ((xi >= 4) != (xj >= 4));
        if (mr || mc) val = -1e9f;
    }
    tbl[idx] = val;
}

// ---------------- K1: QKV GEMM, persistent M-loop ----------------
// grid (98,9): block stages 64x192 B-tile once, loops 4x over 128-row A-tiles
// with double-buffered register A prefetch. q cols (nblk<3) prescaled.
__global__ __launch_bounds__(256) void qkv_gemm5(const bf16_t* __restrict__ xb,
                                                 const bf16_t* __restrict__ wt,
                                                 bf16_t* __restrict__ qkv) {
    __shared__ alignas(16) bf16_t bsh[64 * DIM];     // 24576 B, swizzled layout
    const int nblk = blockIdx.y;
    const int wave = threadIdx.x >> 6, lane = threadIdx.x & 63;
    const int lo = lane & 15, hi = lane >> 4;

    const bf16_t* bt = wt + (size_t)nblk * 64 * DIM;
#pragma unroll
    for (int i = 0; i < 6; i++) {
        int s = wave * 384 + i * 64 + lane;          // 16B chunk index
        int g = s ^ ((s / 24) & 7);                  // pre-swizzled source
        gld_lds16(bt + g * 8, bsh + (wave * 384 + i * 64) * 8);
    }

    const size_t rowbase = (size_t)blockIdx.x * 512 + wave * 32;
    const float qs = (nblk < 3) ? 0.17677669529663687f : 1.0f;   // 1/sqrt(32)

    auto load_tile = [&](bf16x8 (&a)[2][6], int t) {
        const bf16_t* ab = xb + (rowbase + t * 128 + lo) * DIM + hi * 8;
#pragma unroll
        for (int mtl = 0; mtl < 2; mtl++)
#pragma unroll
            for (int ks = 0; ks < 6; ks++)
                a[mtl][ks] = *reinterpret_cast<const bf16x8*>(ab + mtl * 16 * DIM + ks * 32);
    };

    auto compute_store = [&](bf16x8 (&a)[2][6], int t) {
        f32x4 acc[2][4];
#pragma unroll
        for (int mtl = 0; mtl < 2; mtl++)
#pragma unroll
            for (int ct = 0; ct < 4; ct++) acc[mtl][ct] = (f32x4){0.f, 0.f, 0.f, 0.f};
#pragma unroll
        for (int ks = 0; ks < 6; ks++)
#pragma unroll
            for (int ct = 0; ct < 4; ct++) {
                int r = ct * 16 + lo;
                int off = (ks * 64 + hi * 16) ^ ((r & 7) << 4);   // swizzled read
                bf16x8 b = *reinterpret_cast<const bf16x8*>((const char*)bsh + r * 384 + off);
#pragma unroll
                for (int mtl = 0; mtl < 2; mtl++)
                    acc[mtl][ct] = MFMA(a[mtl][ks], b, acc[mtl][ct]);
            }
        const size_t rb = rowbase + t * 128;
#pragma unroll
        for (int mtl = 0; mtl < 2; mtl++)
#pragma unroll
            for (int ct = 0; ct < 4; ct++)
#pragma unroll
                for (int r = 0; r < 4; r++)
                    qkv[(rb + mtl * 16 + hi * 4 + r) * N3 + nblk * 64 + ct * 16 + lo] =
                        (bf16_t)(acc[mtl][ct][r] * qs);
    };

    bf16x8 A0[2][6], A1[2][6];
    load_tile(A0, 0);
    __syncthreads();                                  // B-tile ready

#pragma unroll
    for (int t = 0; t < 4; t += 2) {
        load_tile(A1, t + 1);                         // prefetch while computing t
        compute_store(A0, t);
        if (t + 2 < 4) load_tile(A0, t + 2);
        compute_store(A1, t + 1);
    }
}

// ---------------- K2: attention, 4 waves cooperate on one (window,head) ----------------
__global__ __launch_bounds__(256) void attn_kernel4(const bf16_t* __restrict__ qkv,
                                                    const float* __restrict__ tbl,
                                                    bf16_t* __restrict__ att) {
    const int win = blockIdx.x, h = blockIdx.y, bb = blockIdx.z;
    const int wh = win >> 3, ww = win & 7;
    const int mt = threadIdx.x >> 6;                  // wave id = M-tile id
    const int lane = threadIdx.x & 63;
    const int lo = lane & 15, hi = lane >> 4;

    __shared__ bf16_t P[64][72];                      // per-wave rows; stride 72
    __shared__ alignas(16) bf16_t VT[32][72];         // V transposed [d][token]

    const int variant = ((wh == 7) ? 2 : 0) | ((ww == 7) ? 1 : 0);
    const float* tbase = tbl + ((size_t)variant << 12);

    auto tokoff = [&](int t) -> size_t {
        int ti = t / 7, tj = t % 7;
        return ((size_t)(bb * HW + wh * WS7 + ti) * HW + ww * WS7 + tj) * N3 + h * HD;
    };

    // stage V transposed: thread (mt,lo,hi) loads token t=mt*16+lo, channels hi*8..+8
    {
        const int t = mt * 16 + lo;
        bf16x8 v;
        if (t < NTOK) {
            v = *reinterpret_cast<const bf16x8*>(qkv + tokoff(t) + 2 * DIM + hi * 8);
        } else {
#pragma unroll
            for (int j = 0; j < 8; j++) v[j] = (bf16_t)0.f;
        }
#pragma unroll
        for (int j = 0; j < 8; j++) VT[hi * 8 + j][t] = v[j];
    }

    // Q (own M-tile rows) and K (all 4 column tiles); q pre-scaled in GEMM
    bf16x8 qf, kf[4];
    {
        int t = mt * 16 + lo;
        if (t < NTOK) {
            qf = *reinterpret_cast<const bf16x8*>(qkv + tokoff(t) + hi * 8);
        } else {
#pragma unroll
            for (int j = 0; j < 8; j++) qf[j] = (bf16_t)0.f;
        }
    }
#pragma unroll
    for (int ct = 0; ct < 4; ct++) {
        int t = ct * 16 + lo;
        if (t < NTOK) {
            kf[ct] = *reinterpret_cast<const bf16x8*>(qkv + tokoff(t) + DIM + hi * 8);
        } else {
#pragma unroll
            for (int j = 0; j < 8; j++) kf[ct][j] = (bf16_t)0.f;
        }
    }

    const f32x4 zero4 = {0.f, 0.f, 0.f, 0.f};
    f32x4 s[4];
#pragma unroll
    for (int ct = 0; ct < 4; ct++) s[ct] = MFMA(qf, kf[ct], zero4);

    // softmax over this wave's 4 row-groups
    float rinv[4];
#pragma unroll
    for (int r = 0; r < 4; r++) {
        int ti = mt * 16 + hi * 4 + r;
        const float* trow = tbase + ti * 64 + lo;
        float vals[4];
        float mx = -3e38f;
#pragma unroll
        for (int ct = 0; ct < 4; ct++) {
            float v = s[ct][r] + trow[ct * 16];
            vals[ct] = v;
            mx = fmaxf(mx, v);
        }
#pragma unroll
        for (int off = 1; off < 16; off <<= 1) mx = fmaxf(mx, __shfl_xor(mx, off));
        float sum = 0.f;
#pragma unroll
        for (int ct = 0; ct < 4; ct++) {
            float p = __expf(vals[ct] - mx);
            sum += p;
            P[ti][ct * 16 + lo] = (bf16_t)p;
        }
#pragma unroll
        for (int off = 1; off < 16; off <<= 1) sum += __shfl_xor(sum, off);
        rinv[r] = 1.f / sum;
    }

    __syncthreads();   // VT complete

    // O(16x32) = P(16x64) @ V(64x32): 2 K-steps x 2 col-tiles
    f32x4 o[2] = {zero4, zero4};
#pragma unroll
    for (int ks = 0; ks < 2; ks++) {
        bf16x8 pa = *reinterpret_cast<const bf16x8*>(&P[mt * 16 + lo][ks * 32 + hi * 8]);
#pragma unroll
        for (int c2 = 0; c2 < 2; c2++) {
            bf16x8 vb = *reinterpret_cast<const bf16x8*>(&VT[c2 * 16 + lo][ks * 32 + hi * 8]);
            o[c2] = MFMA(pa, vb, o[c2]);
        }
    }

#pragma unroll
    for (int r = 0; r < 4; r++) {
        int ti = mt * 16 + hi * 4 + r;
        if (ti < NTOK) {
            int y = wh * WS7 + ti / 7, xcol = ww * WS7 + ti % 7;
            size_t aoff = ((size_t)(bb * HW + y) * HW + xcol) * DIM + h * HD;
#pragma unroll
            for (int c2 = 0; c2 < 2; c2++)
                att[aoff + c2 * 16 + lo] = (bf16_t)(o[c2][r] * rinv[r]);
        }
    }
}

// ---------------- K3: out GEMM + bias + roll(+3,+3) ----------------
__global__ __launch_bounds__(256) void out_gemm2(const bf16_t* __restrict__ att,
                                                 const bf16_t* __restrict__ wt,
                                                 const float* __restrict__ bias,
                                                 float* __restrict__ out) {
    __shared__ alignas(16) bf16_t bsh[64 * DIM];
    const int mblk = blockIdx.x, nblk = blockIdx.y;
    const int wave = threadIdx.x >> 6, lane = threadIdx.x & 63;
    const int lo = lane & 15, hi = lane >> 4;

    const bf16_t* bt = wt + (size_t)nblk * 64 * DIM;
#pragma unroll
    for (int i = 0; i < 6; i++) {
        int s = wave * 384 + i * 64 + lane;
        int g = s ^ ((s / 24) & 7);
        gld_lds16(bt + g * 8, bsh + (wave * 384 + i * 64) * 8);
    }

    bf16x8 a[2][6];
    const bf16_t* ab = att + ((size_t)mblk * 128 + wave * 32 + lo) * DIM + hi * 8;
#pragma unroll
    for (int mt = 0; mt < 2; mt++)
#pragma unroll
        for (int ks = 0; ks < 6; ks++)
            a[mt][ks] = *reinterpret_cast<const bf16x8*>(ab + mt * 16 * DIM + ks * 32);

    f32x4 acc[2][4];
#pragma unroll
    for (int mt = 0; mt < 2; mt++)
#pragma unroll
        for (int ct = 0; ct < 4; ct++) acc[mt][ct] = (f32x4){0.f, 0.f, 0.f, 0.f};

    __syncthreads();

#pragma unroll
    for (int ks = 0; ks < 6; ks++)
#pragma unroll
        for (int ct = 0; ct < 4; ct++) {
            int r = ct * 16 + lo;
            int off = (ks * 64 + hi * 16) ^ ((r & 7) << 4);
            bf16x8 b = *reinterpret_cast<const bf16x8*>((const char*)bsh + r * 384 + off);
            acc[0][ct] = MFMA(a[0][ks], b, acc[0][ct]);
            acc[1][ct] = MFMA(a[1][ks], b, acc[1][ct]);
        }

    const int rb = mblk * 128 + wave * 32;
#pragma unroll
    for (int mt = 0; mt < 2; mt++)
#pragma unroll
        for (int r = 0; r < 4; r++) {
            int m = rb + mt * 16 + hi * 4 + r;
            int bb = m / (HW * HW);
            int rem = m - bb * HW * HW;
            int ya = rem / HW, xa = rem - ya * HW;
            int yo = ya + 3; if (yo >= HW) yo -= HW;
            int xo = xa + 3; if (xo >= HW) xo -= HW;
            size_t ob = ((size_t)(bb * HW + yo) * HW + xo) * DIM + nblk * 64;
#pragma unroll
            for (int ct = 0; ct < 4; ct++)
                out[ob + ct * 16 + lo] = acc[mt][ct][r] + bias[nblk * 64 + ct * 16 + lo];
        }
}

extern "C" void kernel_launch(void* const* d_in, const int* in_sizes, int n_in,
                              void* d_out, int out_size, void* d_ws, size_t ws_size,
                              hipStream_t stream) {
    const float* x    = (const float*)d_in[0];
    const float* wqkv = (const float*)d_in[1];
    const float* pe   = (const float*)d_in[2];
    const float* wout = (const float*)d_in[3];
    const float* bout = (const float*)d_in[4];
    float* out = (float*)d_out;

    char* ws = (char*)d_ws;
    const size_t XB_BYTES  = (size_t)NB * HW * HW * DIM * 2;   // 19,267,584
    const size_t QKV_BYTES = (size_t)NB * HW * HW * N3 * 2;    // 57,802,752
    const size_t ATT_BYTES = XB_BYTES;
    const size_t WQ_BYTES  = (size_t)N3 * DIM * 2;
    const size_t WO_BYTES  = (size_t)DIM * DIM * 2;
    bf16_t* xb    = (bf16_t*)ws;
    bf16_t* qkv   = (bf16_t*)(ws + XB_BYTES);
    bf16_t* att   = (bf16_t*)(ws + XB_BYTES + QKV_BYTES);
    bf16_t* wqkvt = (bf16_t*)(ws + XB_BYTES + QKV_BYTES + ATT_BYTES);
    bf16_t* woutt = (bf16_t*)(ws + XB_BYTES + QKV_BYTES + ATT_BYTES + WQ_BYTES);
    float*  tbl   = (float*)(ws + XB_BYTES + QKV_BYTES + ATT_BYTES + WQ_BYTES + WO_BYTES);

    prep_x_kernel<<<(NB * HW * HW * (DIM / 8) + 255) / 256, 256, 0, stream>>>(x, xb);
    prep_w_kernel<<<(N3 * DIM + DIM * DIM + 255) / 256, 256, 0, stream>>>(wqkv, wout, wqkvt, woutt);
    prep_tbl_kernel<<<64, 256, 0, stream>>>(pe, tbl);
    qkv_gemm5<<<dim3(98, 9), 256, 0, stream>>>(xb, wqkvt, qkv);
    attn_kernel4<<<dim3(64, HEADS, NB), 256, 0, stream>>>(qkv, tbl, att);
    out_gemm2<<<dim3(392, 3), 256, 0, stream>>>(att, woutt, bout, out);
}